// Round 6
// baseline (220.733 us; speedup 1.0000x reference)
//
#include <hip/hip_runtime.h>
#include <hip/hip_cooperative_groups.h>

namespace cg = cooperative_groups;

// DecoderAttention, round 6. Algorithm as round 5 (weight math moved off the
// per-edge path by linearity; per-edge cost = one x-row read + 4 dots), now
// fused into a SINGLE cooperative kernel: 256 blocks (=B*H, 1/CU) x 256 thr.
//   A: qk[b,h,:] = (1/8) WK_h^T (WQ_h query_b); zero den/xbar     [block=(b,h)]
//   B: grid-stride 320K edges; dst in glob-set -> wave-cooperative
//      den += exp(qk.x_src), xbar += exp(qk.x_src)*x_src (atomics)
//   C: obar[b,j] = WV[j,:] . (xbar[b,head(j)]/den)               [block=(b,q)]
//   D: out[b,j]  = WO[j,:] . obar[b]                             [block=(b,q)]
// Round-5 evidence: our kernels are all <43us (off the top-5); dur_us is
// dominated by a ~100us harness reset/launch floor (256MiB 0xAA ws-poison
// fills at 6.1TB/s + input restores). This round measures that floor exactly.

#define Dm 256
#define Hh 4

__device__ __forceinline__ float dot4(float4 a, float4 b) {
    return a.x * b.x + a.y * b.y + a.z * b.z + a.w * b.w;
}
__device__ __forceinline__ float wredsum(float p) {
#pragma unroll
    for (int off = 1; off <= 32; off <<= 1) p += __shfl_xor(p, off, 64);
    return p;
}

__global__ __launch_bounds__(256)
void k_fused(const float* __restrict__ query, const float* __restrict__ x,
             const float* __restrict__ WQ, const float* __restrict__ WK,
             const float* __restrict__ WV, const float* __restrict__ WO,
             const int* __restrict__ src, const int* __restrict__ dst,
             const int* __restrict__ glob, float* __restrict__ qk,
             float* __restrict__ xbar, float* __restrict__ den,
             float* __restrict__ obar, float* __restrict__ out,
             int B, int ne) {
    cg::grid_group grid = cg::this_grid();
    int g = blockIdx.x, t = threadIdx.x, w = t >> 6, lane = t & 63;
    __shared__ float sQ[64];
    __shared__ float4 spart[4][64];
    __shared__ int sglob[256];
    __shared__ float4 sx4[Hh * Dm / 4];          // 4KB staging, reused by C/D
    float* sx = (float*)sx4;

    // ---------------- Phase A: qk + zeroing ----------------
    int b = g >> 2, h = g & 3;
    xbar[(size_t)g * Dm + t] = 0.f;              // zero my (b,h) slice
    if (t == 0) den[g] = 0.f;
    float4 qa = reinterpret_cast<const float4*>(query + (size_t)b * Dm)[lane];
#pragma unroll 4
    for (int i = 0; i < 16; ++i) {               // Qh[r] = WQ[h*64+r,:].query_b
        int r = w * 16 + i;
        float4 ww = reinterpret_cast<const float4*>(WQ + (size_t)(h * 64 + r) * Dm)[lane];
        float p = wredsum(dot4(ww, qa));
        if (lane == 0) sQ[r] = p;
    }
    __syncthreads();
    float4 acc = make_float4(0.f, 0.f, 0.f, 0.f);
#pragma unroll 4
    for (int i = 0; i < 16; ++i) {               // qk[c] = sum_r Qh[r]*WK[r,c]
        int r = w * 16 + i;
        float qv = sQ[r];
        float4 kw = reinterpret_cast<const float4*>(WK + (size_t)(h * 64 + r) * Dm)[lane];
        acc.x += qv * kw.x; acc.y += qv * kw.y; acc.z += qv * kw.z; acc.w += qv * kw.w;
    }
    spart[w][lane] = acc;
    __syncthreads();
    if (t < 64) {
        float4 s0 = spart[0][t], s1 = spart[1][t], s2 = spart[2][t], s3 = spart[3][t];
        float4 s = make_float4((s0.x + s1.x + s2.x + s3.x) * 0.125f,  // fold 1/sqrt(DK)
                               (s0.y + s1.y + s2.y + s3.y) * 0.125f,
                               (s0.z + s1.z + s2.z + s3.z) * 0.125f,
                               (s0.w + s1.w + s2.w + s3.w) * 0.125f);
        reinterpret_cast<float4*>(qk + (size_t)g * Dm)[t] = s;
    }
    if (t < B) sglob[t] = glob[t];
    grid.sync();

    // ---------------- Phase B: edge scan + aggregation ----------------
    int stride = gridDim.x * 256;
    for (int e = g * 256 + t; e - t < ne; e += stride) {
        int d = (e < ne) ? dst[e] : -1;
        int bb = -1;
        for (int j = 0; j < B; ++j)
            if (sglob[j] == d) bb = j;
        int sv = (bb >= 0) ? src[e] : 0;
        unsigned long long mask = __ballot(bb >= 0);
        while (mask) {
            int j = __ffsll(mask) - 1;
            mask &= mask - 1;
            int eb = __shfl(bb, j, 64);
            int es = __shfl(sv, j, 64);
            float4 xa = reinterpret_cast<const float4*>(x + (size_t)es * Dm)[lane];
#pragma unroll
            for (int h2 = 0; h2 < Hh; ++h2) {
                float4 q4 = reinterpret_cast<const float4*>(qk + (size_t)(eb * Hh + h2) * Dm)[lane];
                float p = wredsum(dot4(q4, xa));
                float wexp = __expf(p);          // |s| small: softmax w/o max shift
                if (lane == 0) atomicAdd(&den[eb * Hh + h2], wexp);
                float* xb = xbar + (size_t)(eb * Hh + h2) * Dm + lane * 4;
                atomicAdd(xb + 0, wexp * xa.x);
                atomicAdd(xb + 1, wexp * xa.y);
                atomicAdd(xb + 2, wexp * xa.z);
                atomicAdd(xb + 3, wexp * xa.w);
            }
        }
    }
    grid.sync();

    // ---------------- Phase C: obar rows [q*64, q*64+64) of node b ----------
    int q = g & 3;
    for (int i = t; i < Hh * Dm; i += 256) {     // stage xhat = xbar/den in LDS
        int hh = i >> 8;
        float dv = den[b * Hh + hh];
        sx[i] = dv > 0.f ? xbar[(size_t)(b * Hh + hh) * Dm + (i & 255)] / dv : 0.f;
    }
    __syncthreads();
#pragma unroll 4
    for (int i = 0; i < 16; ++i) {
        int j = q * 64 + w * 16 + i;             // output row, head j>>6
        float4 wv = reinterpret_cast<const float4*>(WV + (size_t)j * Dm)[lane];
        float4 xh = reinterpret_cast<const float4*>(sx + (j >> 6) * Dm)[lane];
        float p = wredsum(dot4(wv, xh));
        if (lane == 0) obar[(size_t)b * Dm + j] = p;
    }
    grid.sync();

    // ---------------- Phase D: out rows [q*64, q*64+64) of node b -----------
    __syncthreads();                             // done with sx before reuse
    if (t < 64) sx4[t] = reinterpret_cast<const float4*>(obar + (size_t)b * Dm)[t];
    __syncthreads();
#pragma unroll 4
    for (int i = 0; i < 16; ++i) {
        int j = q * 64 + w * 16 + i;
        float4 wo = reinterpret_cast<const float4*>(WO + (size_t)j * Dm)[lane];
        float p = wredsum(dot4(wo, sx4[lane]));
        if (lane == 0) out[(size_t)b * Dm + j] = p;
    }
}

extern "C" void kernel_launch(void* const* d_in, const int* in_sizes, int n_in,
                              void* d_out, int out_size, void* d_ws, size_t ws_size,
                              hipStream_t stream) {
    const float* query = (const float*)d_in[0];
    const float* x     = (const float*)d_in[1];
    const float* WQ    = (const float*)d_in[2];
    const float* WK    = (const float*)d_in[3];
    const float* WV    = (const float*)d_in[4];
    const float* WO    = (const float*)d_in[5];
    const int*   src   = (const int*)d_in[6];
    const int*   dst   = (const int*)d_in[7];
    const int*   glob  = (const int*)d_in[8];
    float*       out   = (float*)d_out;

    int B  = in_sizes[8];
    int NE = in_sizes[6];

    // ws layout (floats): qk[B*H*Dm] | den[B*H] | obar[B*Dm] | xbar[B*H*Dm]
    float* qk   = (float*)d_ws;
    float* den  = qk + (size_t)B * Hh * Dm;
    float* obar = den + (size_t)B * Hh;
    float* xbar = obar + (size_t)B * Dm;

    void* args[] = {&query, &x, &WQ, &WK, &WV, &WO, &src, &dst, &glob,
                    &qk, &xbar, &den, &obar, &out, &B, &NE};
    hipLaunchCooperativeKernel(reinterpret_cast<void*>(k_fused),
                               dim3(B * Hh), dim3(256), args, 0, stream);
}

// Round 7
// 134.467 us; speedup vs baseline: 1.6415x; 1.6415x over previous
//
#include <hip/hip_runtime.h>

// DecoderAttention, round 7. Round-5 3-kernel structure (best so far) with the
// per-edge membership test upgraded from a 64-iter LDS search to an O(1)
// VERIFIED hash: k_prep scatters inv[glob[b]]=b (no init pass: a candidate
// cand=inv[d] is accepted only if cand in [0,B) AND sglob[cand]==d, which is
// exact because glob values are distinct — poison garbage can't false-positive).
// Round-6 lesson: cooperative fusion regressed (grid.sync cost + 5x less TLP
// on the edge scan); dur_us carries a ~90us harness ws-poison floor we can't
// touch, so target = sum of kernels + gaps (~25us -> ~15us).
//
// Algorithm (linearity, from round 5):
//   score:  s[e,h] = (WK_h^T q_h) . x_e       (qk precomputed per (b,h))
//   value:  sum_e alpha*(WV_h x_e) = WV_h . (sum_e alpha*x_e)
// Per edge: one 1KB x-row + 4 dots against L2-hot qk. No weight traffic.

#define Dm 256
#define Hh 4

__device__ __forceinline__ float dot4(float4 a, float4 b) {
    return a.x * b.x + a.y * b.y + a.z * b.z + a.w * b.w;
}
__device__ __forceinline__ float wredsum(float p) {
#pragma unroll
    for (int off = 1; off <= 32; off <<= 1) p += __shfl_xor(p, off, 64);
    return p;
}

// Blocks [0, B*H): qk[b,h,:] = (1/8) * WK_h^T (WQ_h query_b).
// Blocks [B*H, ...): zero xbar/den; scatter inv[glob[b]] = b.
__global__ __launch_bounds__(256)
void k_prep(const float* __restrict__ query, const float* __restrict__ WQ,
            const float* __restrict__ WK, const int* __restrict__ glob,
            float* __restrict__ qk, float* __restrict__ xbar,
            float* __restrict__ den, int* __restrict__ inv, int B) {
    int t = threadIdx.x, w = t >> 6, lane = t & 63;
    int nq = B * Hh;
    if ((int)blockIdx.x >= nq) {
        int zi = ((int)blockIdx.x - nq) * 256 + t;
        if (zi < nq * Dm) xbar[zi] = 0.f;
        if (zi < nq) den[zi] = 0.f;
        if (zi < B) inv[glob[zi]] = zi;      // only writes; rest stays garbage
        return;
    }
    int b = blockIdx.x / Hh, h = blockIdx.x % Hh;
    __shared__ float sQ[64];
    __shared__ float4 spart[4][64];
    float4 qa = reinterpret_cast<const float4*>(query + (size_t)b * Dm)[lane];
    // Phase 1: Qh[r] = WQ[h*64+r,:] . query[b]; wave w does rows w*16..w*16+15.
#pragma unroll 4
    for (int i = 0; i < 16; ++i) {
        int r = w * 16 + i;
        float4 ww = reinterpret_cast<const float4*>(WQ + (size_t)(h * 64 + r) * Dm)[lane];
        float p = wredsum(dot4(ww, qa));
        if (lane == 0) sQ[r] = p;
    }
    __syncthreads();
    // Phase 2: qk[c] = sum_r Qh[r] * WK[h*64+r, c]; coalesced row loads.
    float4 acc = make_float4(0.f, 0.f, 0.f, 0.f);
#pragma unroll 4
    for (int i = 0; i < 16; ++i) {
        int r = w * 16 + i;
        float qv = sQ[r];
        float4 kw = reinterpret_cast<const float4*>(WK + (size_t)(h * 64 + r) * Dm)[lane];
        acc.x += qv * kw.x; acc.y += qv * kw.y; acc.z += qv * kw.z; acc.w += qv * kw.w;
    }
    spart[w][lane] = acc;
    __syncthreads();
    if (t < 64) {
        float4 s0 = spart[0][t], s1 = spart[1][t], s2 = spart[2][t], s3 = spart[3][t];
        float4 s = make_float4((s0.x + s1.x + s2.x + s3.x) * 0.125f,  // fold 1/sqrt(DK)
                               (s0.y + s1.y + s2.y + s3.y) * 0.125f,
                               (s0.z + s1.z + s2.z + s3.z) * 0.125f,
                               (s0.w + s1.w + s2.w + s3.w) * 0.125f);
        reinterpret_cast<float4*>(qk + (size_t)(b * Hh + h) * Dm)[t] = s;
    }
}

// One edge per thread. Membership: cand = inv[dst[e]] (L2-resident gather),
// verified against sglob. Matched edges processed wave-cooperatively.
__global__ __launch_bounds__(256)
void k_edges(const int* __restrict__ src, const int* __restrict__ dst,
             const int* __restrict__ glob, const int* __restrict__ inv,
             const float* __restrict__ x, const float* __restrict__ qk,
             float* __restrict__ xbar, float* __restrict__ den,
             int B, int ne) {
    int t = threadIdx.x, lane = t & 63;
    __shared__ int sglob[64];
    if (t < B) sglob[t] = glob[t];
    __syncthreads();
    int e = blockIdx.x * 256 + t;
    int bb = -1, sv = 0;
    if (e < ne) {
        int d = dst[e];
        int cand = inv[d];                       // O(1) hash probe
        if (cand >= 0 && cand < B && sglob[cand] == d) bb = cand;  // exact verify
        if (bb >= 0) sv = src[e];                // load src only when matched
    }
    unsigned long long mask = __ballot(bb >= 0);
    while (mask) {
        int j = __ffsll(mask) - 1;
        mask &= mask - 1;
        int eb = __shfl(bb, j, 64);
        int es = __shfl(sv, j, 64);
        float4 xa = reinterpret_cast<const float4*>(x + (size_t)es * Dm)[lane];
#pragma unroll
        for (int h = 0; h < Hh; ++h) {
            float4 q4 = reinterpret_cast<const float4*>(qk + (size_t)(eb * Hh + h) * Dm)[lane];
            float p = wredsum(dot4(q4, xa));
            float wexp = __expf(p);              // |s| small: softmax w/o max shift
            if (lane == 0) atomicAdd(&den[eb * Hh + h], wexp);
            float* xb = xbar + (size_t)(eb * Hh + h) * Dm + lane * 4;
            atomicAdd(xb + 0, wexp * xa.x);
            atomicAdd(xb + 1, wexp * xa.y);
            atomicAdd(xb + 2, wexp * xa.z);
            atomicAdd(xb + 3, wexp * xa.w);
        }
    }
}

// Per global node: obar[j] = WV[j,:] . (xbar[h]/den[h]), then out = WO . obar.
// 1024 threads = 16 waves; each wave does 16 coalesced row-dots per phase.
__global__ __launch_bounds__(1024)
void k_final(const float* __restrict__ xbar, const float* __restrict__ den,
             const float* __restrict__ WV, const float* __restrict__ WO,
             float* __restrict__ out) {
    int b = blockIdx.x, t = threadIdx.x, w = t >> 6, lane = t & 63;
    __shared__ float sx[Hh * Dm];
    __shared__ float sobar[Dm];
    if (t < Hh * Dm) {
        int h = t >> 8;
        float dv = den[b * Hh + h];
        sx[t] = dv > 0.f ? xbar[(size_t)(b * Hh + h) * Dm + (t & 255)] / dv : 0.f;
    }
    __syncthreads();
#pragma unroll 4
    for (int i = 0; i < 16; ++i) {
        int j = w * 16 + i;                      // output row 0..255, head j>>6
        float4 wv = reinterpret_cast<const float4*>(WV + (size_t)j * Dm)[lane];
        float4 xb = reinterpret_cast<const float4*>(sx + (j >> 6) * Dm)[lane];
        float p = wredsum(dot4(wv, xb));
        if (lane == 0) sobar[j] = p;
    }
    __syncthreads();
#pragma unroll 4
    for (int i = 0; i < 16; ++i) {
        int j = w * 16 + i;
        float4 wo = reinterpret_cast<const float4*>(WO + (size_t)j * Dm)[lane];
        float4 ob = reinterpret_cast<const float4*>(sobar)[lane];
        float p = wredsum(dot4(wo, ob));
        if (lane == 0) out[(size_t)b * Dm + j] = p;
    }
}

extern "C" void kernel_launch(void* const* d_in, const int* in_sizes, int n_in,
                              void* d_out, int out_size, void* d_ws, size_t ws_size,
                              hipStream_t stream) {
    const float* query = (const float*)d_in[0];
    const float* x     = (const float*)d_in[1];
    const float* WQ    = (const float*)d_in[2];
    const float* WK    = (const float*)d_in[3];
    const float* WV    = (const float*)d_in[4];
    const float* WO    = (const float*)d_in[5];
    const int*   src   = (const int*)d_in[6];
    const int*   dst   = (const int*)d_in[7];
    const int*   glob  = (const int*)d_in[8];

    int B  = in_sizes[8];
    int NV = in_sizes[1] / Dm;
    int NE = in_sizes[6];

    // ws layout (4B elems): qk[B*H*Dm] | den[B*H] | xbar[B*H*Dm] | inv[NV]
    float* qk   = (float*)d_ws;
    float* den  = qk + (size_t)B * Hh * Dm;
    float* xbar = den + (size_t)B * Hh;
    int*   inv  = (int*)(xbar + (size_t)B * Hh * Dm);
    float* out  = (float*)d_out;

    int nq = B * Hh;
    int zblocks = (nq * Dm + 255) / 256;
    k_prep<<<nq + zblocks, 256, 0, stream>>>(query, WQ, WK, glob, qk, xbar, den, inv, B);
    k_edges<<<(NE + 255) / 256, 256, 0, stream>>>(src, dst, glob, inv, x, qk, xbar, den, B, NE);
    k_final<<<B, 1024, 0, stream>>>(xbar, den, WV, WO, out);
}